// Round 6
// baseline (197.852 us; speedup 1.0000x reference)
//
#include <hip/hip_runtime.h>
#include <hip/hip_fp16.h>

#define ALPHA 0.2f
static constexpr int NN = 50000;
static constexpr long NE = (long)NN * 32;
static constexpr int TILES = 4;
static constexpr int TILE_N = NN / TILES;      // 12500 rows = 3.2 MB/slice

typedef float f4v __attribute__((ext_vector_type(4)));
typedef float f2v __attribute__((ext_vector_type(2)));

// workspace layout (float offsets)
static constexpr long WS_HN1 = 0;
static constexpr long WS_HN2 = NN;
static constexpr long WS_HE1 = 2L * NN;
static constexpr long WS_ST  = 3L * NN;        // 2*NN: [sum nn^2][sum ne^2]
static constexpr long WS_P   = 5L * NN;        // 512 floats of partials
static constexpr long WS_HEV = 250560;         // __half[NN*128]; 250560*4 % 256 == 0

// ---- kernel 1: h_v GEMM (50000x256 @ 256x64) + f16 pack + attention dots ----
__global__ __launch_bounds__(256) void k_hv(const float* __restrict__ A,
                                            const float* __restrict__ W,
                                            const float* __restrict__ a_node,
                                            const float* __restrict__ a_edge,
                                            __half* __restrict__ hev,
                                            float* __restrict__ hn1,
                                            float* __restrict__ hn2,
                                            float* __restrict__ he1) {
    __shared__ float As[16][65];
    __shared__ float Ws[16][64];
    const int t  = threadIdx.x;
    const int m0 = blockIdx.x * 64;
    const int tr = t >> 4, tc = t & 15;
    const int lr = t >> 2, seg = t & 3;
    const int wk = t >> 4, wc = t & 15;

    float acc[4][4] = {};
    for (int k0 = 0; k0 < 256; k0 += 16) {
        int row = m0 + lr;
        float4 av = make_float4(0.f, 0.f, 0.f, 0.f);
        if (row < NN)
            av = *reinterpret_cast<const float4*>(&A[(long)row * 256 + k0 + seg * 4]);
        As[seg*4+0][lr] = av.x; As[seg*4+1][lr] = av.y;
        As[seg*4+2][lr] = av.z; As[seg*4+3][lr] = av.w;
        *reinterpret_cast<float4*>(&Ws[wk][wc*4]) =
            *reinterpret_cast<const float4*>(&W[(k0 + wk) * 64 + wc * 4]);
        __syncthreads();
        #pragma unroll
        for (int kk = 0; kk < 16; ++kk) {
            float a0 = As[kk][tr*4+0], a1 = As[kk][tr*4+1];
            float a2 = As[kk][tr*4+2], a3 = As[kk][tr*4+3];
            float b0 = Ws[kk][tc*4+0], b1 = Ws[kk][tc*4+1];
            float b2 = Ws[kk][tc*4+2], b3 = Ws[kk][tc*4+3];
            acc[0][0] += a0*b0; acc[0][1] += a0*b1; acc[0][2] += a0*b2; acc[0][3] += a0*b3;
            acc[1][0] += a1*b0; acc[1][1] += a1*b1; acc[1][2] += a1*b2; acc[1][3] += a1*b3;
            acc[2][0] += a2*b0; acc[2][1] += a2*b1; acc[2][2] += a2*b2; acc[2][3] += a2*b3;
            acc[3][0] += a3*b0; acc[3][1] += a3*b1; acc[3][2] += a3*b2; acc[3][3] += a3*b3;
        }
        __syncthreads();
    }

    float an1[4], an2[4], ae1[4];
    #pragma unroll
    for (int j = 0; j < 4; ++j) {
        an1[j] = a_node[tc*4 + j];
        an2[j] = a_node[64 + tc*4 + j];
        ae1[j] = a_edge[tc*4 + j];
    }

    #pragma unroll
    for (int q = 0; q < 4; ++q) {
        float p1 = 0.f, p2 = 0.f, p3 = 0.f;
        #pragma unroll
        for (int j = 0; j < 4; ++j) {
            p1 += acc[q][j] * an1[j];
            p2 += acc[q][j] * an2[j];
            p3 += acc[q][j] * ae1[j];
        }
        #pragma unroll
        for (int m = 1; m <= 8; m <<= 1) {
            p1 += __shfl_xor(p1, m);
            p2 += __shfl_xor(p2, m);
            p3 += __shfl_xor(p3, m);
        }
        int row = m0 + tr * 4 + q;
        if (row < NN) {
            ushort4 hp;
            hp.x = __half_as_ushort(__float2half(acc[q][0]));
            hp.y = __half_as_ushort(__float2half(acc[q][1]));
            hp.z = __half_as_ushort(__float2half(acc[q][2]));
            hp.w = __half_as_ushort(__float2half(acc[q][3]));
            *reinterpret_cast<ushort4*>(&hev[(long)row * 128 + tc * 4]) = hp;
            if (tc == 0) { hn1[row] = p1; hn2[row] = p2; he1[row] = p3; }
        }
    }
}

// ---- kernel 2: e_v rows 0..49999 -> f16 second half of hev ----
__global__ __launch_bounds__(256) void k_ev(const float* __restrict__ ef,
                                            const float* __restrict__ We,
                                            __half* __restrict__ hev) {
    const int lane = threadIdx.x & 63, w = threadIdx.x >> 6;
    const int r = blockIdx.x * 4 + w;
    float acc = 0.f;
    #pragma unroll
    for (int k = 0; k < 32; ++k)
        acc += ef[(long)r * 32 + k] * We[k * 64 + lane];
    hev[(long)r * 128 + 64 + lane] = __float2half(acc);
}

// ---- kernel 3: attention + dst-range-tiled gather ----
// Gather range confined to one 3.2 MB slice per phase so it L2-fits per XCD;
// next-tile issue overlaps current-tile drain. All tile branches are
// wave-uniform (dst via readlane -> SGPR compare), so no divergence.
__global__ __launch_bounds__(256) void k_edge(const float* __restrict__ ef,
                                              const int*   __restrict__ edges,
                                              const float* __restrict__ a_edge,
                                              const float* __restrict__ hn1,
                                              const float* __restrict__ hn2,
                                              const float* __restrict__ he1,
                                              const __half* __restrict__ hev,
                                              float* __restrict__ st,
                                              float* __restrict__ out) {
    const int t = threadIdx.x;
    const int w = t >> 6, l = t & 63;
    const int n = blockIdx.x * 4 + w;
    const int i = l >> 1, h = l & 1;          // lane pair (2i,2i+1) owns edge i
    const long ebase = (long)n * 32;

    // (1) dst index first — gather addresses depend on it
    const int d = __builtin_nontemporal_load(&edges[(ebase + i) * 2 + 1]);

    // (2) streaming ef loads (nt: single-use, keep out of L2)
    const f4v* efb = reinterpret_cast<const f4v*>(&ef[(ebase + i) * 32 + h * 16]);
    f4v v0 = __builtin_nontemporal_load(efb + 0);
    f4v v1 = __builtin_nontemporal_load(efb + 1);
    f4v v2 = __builtin_nontemporal_load(efb + 2);
    f4v v3 = __builtin_nontemporal_load(efb + 3);

    // (3) issue tile-0 gathers (overlap with softmax compute below)
    __half2 h2[32];
    #pragma unroll
    for (int u = 0; u < 32; ++u) {
        int du = __builtin_amdgcn_readlane(d, 2 * u);
        if (du < TILE_N)
            h2[u] = *reinterpret_cast<const __half2*>(&hev[(long)du * 128 + l * 2]);
    }

    // (4) attention compute
    float dot;
    {
        const float* ae = &a_edge[64 + h * 16];
        float4 a0q = *reinterpret_cast<const float4*>(ae);
        float4 a1q = *reinterpret_cast<const float4*>(ae + 4);
        float4 a2q = *reinterpret_cast<const float4*>(ae + 8);
        float4 a3q = *reinterpret_cast<const float4*>(ae + 12);
        dot = v0.x*a0q.x + v0.y*a0q.y + v0.z*a0q.z + v0.w*a0q.w
            + v1.x*a1q.x + v1.y*a1q.y + v1.z*a1q.z + v1.w*a1q.w
            + v2.x*a2q.x + v2.y*a2q.y + v2.z*a2q.z + v2.w*a2q.w
            + v3.x*a3q.x + v3.y*a3q.y + v3.z*a3q.z + v3.w*a3q.w;
    }
    dot += __shfl_xor(dot, 1);

    float attn = hn1[n] + hn2[d];
    attn = attn >= 0.f ? attn : ALPHA * attn;
    float wn = __expf(fminf(fmaxf(attn, -2.f), 2.f));

    float atte = he1[n] + dot;
    atte = atte >= 0.f ? atte : ALPHA * atte;
    float we = __expf(fminf(fmaxf(atte, -2.f), 2.f));

    float dn = wn, de = we;
    #pragma unroll
    for (int m = 2; m <= 32; m <<= 1) { dn += __shfl_xor(dn, m); de += __shfl_xor(de, m); }
    float nn = wn / dn, ne = we / de;

    float sqn = nn * nn, sqe = ne * ne;
    #pragma unroll
    for (int m = 2; m <= 32; m <<= 1) { sqn += __shfl_xor(sqn, m); sqe += __shfl_xor(sqe, m); }
    if (l == 0) { st[n] = sqn; st[NN + n] = sqe; }

    __half2 wpk = __floats2half2_rn(nn, ne);
    unsigned int wbits = *reinterpret_cast<unsigned int*>(&wpk);

    // (5) tiled drain: drain tile T while tile T+1's loads are in flight
    const bool isE = l >= 32;
    float a0 = 0.f, a1 = 0.f;
    #pragma unroll
    for (int tile = 0; tile < TILES; ++tile) {
        if (tile + 1 < TILES) {
            const int lo = (tile + 1) * TILE_N, hi = lo + TILE_N;
            #pragma unroll
            for (int u = 0; u < 32; ++u) {
                int du = __builtin_amdgcn_readlane(d, 2 * u);
                if (du >= lo && du < hi)
                    h2[u] = *reinterpret_cast<const __half2*>(&hev[(long)du * 128 + l * 2]);
            }
        }
        const int lo = tile * TILE_N, hi = lo + TILE_N;
        #pragma unroll
        for (int u = 0; u < 32; ++u) {
            int du = __builtin_amdgcn_readlane(d, 2 * u);
            if (du >= lo && du < hi) {
                unsigned int wv = (unsigned int)__builtin_amdgcn_readlane((int)wbits, 2 * u);
                __half2 wp = *reinterpret_cast<__half2*>(&wv);
                float wt = isE ? __high2float(wp) : __low2float(wp);
                float2 f = __half22float2(h2[u]);
                a0 = fmaf(wt, f.x, a0);
                a1 = fmaf(wt, f.y, a1);
            }
        }
    }

    long off = isE ? ((long)NN * 64 + (long)n * 64 + (l - 32) * 2)
                   : ((long)n * 64 + l * 2);
    f2v o; o.x = a0; o.y = a1;
    __builtin_nontemporal_store(o, reinterpret_cast<f2v*>(&out[off]));
}

// ---- kernel 4a: stats reduction stage 1 ----
__global__ __launch_bounds__(256) void k_red1(const float* __restrict__ st,
                                              float* __restrict__ part) {
    const int t = threadIdx.x;
    const int n = blockIdx.x * 256 + t;
    float v0 = 0.f, v1 = 0.f;
    if (n < NN) { v0 = st[n]; v1 = st[NN + n]; }
    #pragma unroll
    for (int m = 1; m <= 32; m <<= 1) { v0 += __shfl_xor(v0, m); v1 += __shfl_xor(v1, m); }
    __shared__ float ls[4][2];
    const int wv = t >> 6;
    if ((t & 63) == 0) { ls[wv][0] = v0; ls[wv][1] = v1; }
    __syncthreads();
    if (t == 0) {
        part[(long)blockIdx.x * 2]     = ls[0][0] + ls[1][0] + ls[2][0] + ls[3][0];
        part[(long)blockIdx.x * 2 + 1] = ls[0][1] + ls[1][1] + ls[2][1] + ls[3][1];
    }
}

// ---- kernel 4b: final variances ----
__global__ __launch_bounds__(64) void k_red2(const float* __restrict__ part,
                                             float* __restrict__ out) {
    const int t = threadIdx.x;
    double v0 = 0.0, v1 = 0.0;
    for (int b = t; b < 196; b += 64) {
        v0 += (double)part[b * 2];
        v1 += (double)part[b * 2 + 1];
    }
    #pragma unroll
    for (int m = 1; m <= 32; m <<= 1) { v0 += __shfl_xor(v0, m); v1 += __shfl_xor(v1, m); }
    if (t == 0) {
        const double M = (double)NE;
        const double corr = (double)NN * (double)NN / M;   // (sum w)^2/M, sum w == NN
        out[6400000] = (float)((v0 - corr) / (M - 1.0));
        out[6400001] = (float)((v1 - corr) / (M - 1.0));
    }
}

extern "C" void kernel_launch(void* const* d_in, const int* in_sizes, int n_in,
                              void* d_out, int out_size, void* d_ws, size_t ws_size,
                              hipStream_t stream) {
    const float* node_fts = (const float*)d_in[0];
    const float* edge_fts = (const float*)d_in[1];
    const int*   edges    = (const int*)  d_in[2];
    const float* W_node   = (const float*)d_in[3];
    const float* W_edge   = (const float*)d_in[4];
    const float* a_node   = (const float*)d_in[5];
    const float* a_edge   = (const float*)d_in[6];
    float* out = (float*)d_out;
    float* ws  = (float*)d_ws;

    float*  hn1 = ws + WS_HN1;
    float*  hn2 = ws + WS_HN2;
    float*  he1 = ws + WS_HE1;
    float*  st  = ws + WS_ST;
    float*  prt = ws + WS_P;
    __half* hev = (__half*)(ws + WS_HEV);

    k_hv  <<<(NN + 63) / 64, 256, 0, stream>>>(node_fts, W_node, a_node, a_edge,
                                               hev, hn1, hn2, he1);
    k_ev  <<<NN / 4, 256, 0, stream>>>(edge_fts, W_edge, hev);
    k_edge<<<NN / 4, 256, 0, stream>>>(edge_fts, edges, a_edge, hn1, hn2, he1,
                                       hev, st, out);
    k_red1<<<196, 256, 0, stream>>>(st, prt);
    k_red2<<<1, 64, 0, stream>>>(prt, out);
}

// Round 7
// 166.135 us; speedup vs baseline: 1.1909x; 1.1909x over previous
//
#include <hip/hip_runtime.h>
#include <hip/hip_fp16.h>

#define ALPHA 0.2f
static constexpr int NN = 50000;
static constexpr long NE = (long)NN * 32;
static constexpr int TILES = 4;
static constexpr int TILE_N = NN / TILES;      // 12500 rows = 3.2 MB/slice

typedef float f4v __attribute__((ext_vector_type(4)));
typedef float f2v __attribute__((ext_vector_type(2)));

// workspace layout (float offsets)
static constexpr long WS_HN1 = 0;
static constexpr long WS_HN2 = NN;
static constexpr long WS_HE1 = 2L * NN;
static constexpr long WS_ST  = 3L * NN;        // 2*NN: [sum nn^2][sum ne^2]
static constexpr long WS_P   = 5L * NN;        // 512 floats of partials
static constexpr long WS_HEV = 250560;         // __half[NN*128]; 250560*4 % 256 == 0

// ---- kernel 1: h_v GEMM (50000x256 @ 256x64) + f16 pack + attention dots ----
__global__ __launch_bounds__(256) void k_hv(const float* __restrict__ A,
                                            const float* __restrict__ W,
                                            const float* __restrict__ a_node,
                                            const float* __restrict__ a_edge,
                                            __half* __restrict__ hev,
                                            float* __restrict__ hn1,
                                            float* __restrict__ hn2,
                                            float* __restrict__ he1) {
    __shared__ float As[16][65];
    __shared__ float Ws[16][64];
    const int t  = threadIdx.x;
    const int m0 = blockIdx.x * 64;
    const int tr = t >> 4, tc = t & 15;
    const int lr = t >> 2, seg = t & 3;
    const int wk = t >> 4, wc = t & 15;

    float acc[4][4] = {};
    for (int k0 = 0; k0 < 256; k0 += 16) {
        int row = m0 + lr;
        float4 av = make_float4(0.f, 0.f, 0.f, 0.f);
        if (row < NN)
            av = *reinterpret_cast<const float4*>(&A[(long)row * 256 + k0 + seg * 4]);
        As[seg*4+0][lr] = av.x; As[seg*4+1][lr] = av.y;
        As[seg*4+2][lr] = av.z; As[seg*4+3][lr] = av.w;
        *reinterpret_cast<float4*>(&Ws[wk][wc*4]) =
            *reinterpret_cast<const float4*>(&W[(k0 + wk) * 64 + wc * 4]);
        __syncthreads();
        #pragma unroll
        for (int kk = 0; kk < 16; ++kk) {
            float a0 = As[kk][tr*4+0], a1 = As[kk][tr*4+1];
            float a2 = As[kk][tr*4+2], a3 = As[kk][tr*4+3];
            float b0 = Ws[kk][tc*4+0], b1 = Ws[kk][tc*4+1];
            float b2 = Ws[kk][tc*4+2], b3 = Ws[kk][tc*4+3];
            acc[0][0] += a0*b0; acc[0][1] += a0*b1; acc[0][2] += a0*b2; acc[0][3] += a0*b3;
            acc[1][0] += a1*b0; acc[1][1] += a1*b1; acc[1][2] += a1*b2; acc[1][3] += a1*b3;
            acc[2][0] += a2*b0; acc[2][1] += a2*b1; acc[2][2] += a2*b2; acc[2][3] += a2*b3;
            acc[3][0] += a3*b0; acc[3][1] += a3*b1; acc[3][2] += a3*b2; acc[3][3] += a3*b3;
        }
        __syncthreads();
    }

    float an1[4], an2[4], ae1[4];
    #pragma unroll
    for (int j = 0; j < 4; ++j) {
        an1[j] = a_node[tc*4 + j];
        an2[j] = a_node[64 + tc*4 + j];
        ae1[j] = a_edge[tc*4 + j];
    }

    #pragma unroll
    for (int q = 0; q < 4; ++q) {
        float p1 = 0.f, p2 = 0.f, p3 = 0.f;
        #pragma unroll
        for (int j = 0; j < 4; ++j) {
            p1 += acc[q][j] * an1[j];
            p2 += acc[q][j] * an2[j];
            p3 += acc[q][j] * ae1[j];
        }
        #pragma unroll
        for (int m = 1; m <= 8; m <<= 1) {
            p1 += __shfl_xor(p1, m);
            p2 += __shfl_xor(p2, m);
            p3 += __shfl_xor(p3, m);
        }
        int row = m0 + tr * 4 + q;
        if (row < NN) {
            ushort4 hp;
            hp.x = __half_as_ushort(__float2half(acc[q][0]));
            hp.y = __half_as_ushort(__float2half(acc[q][1]));
            hp.z = __half_as_ushort(__float2half(acc[q][2]));
            hp.w = __half_as_ushort(__float2half(acc[q][3]));
            *reinterpret_cast<ushort4*>(&hev[(long)row * 128 + tc * 4]) = hp;
            if (tc == 0) { hn1[row] = p1; hn2[row] = p2; he1[row] = p3; }
        }
    }
}

// ---- kernel 2: e_v rows 0..49999 -> f16 second half of hev ----
__global__ __launch_bounds__(256) void k_ev(const float* __restrict__ ef,
                                            const float* __restrict__ We,
                                            __half* __restrict__ hev) {
    const int lane = threadIdx.x & 63, w = threadIdx.x >> 6;
    const int r = blockIdx.x * 4 + w;
    float acc = 0.f;
    #pragma unroll
    for (int k = 0; k < 32; ++k)
        acc += ef[(long)r * 32 + k] * We[k * 64 + lane];
    hev[(long)r * 128 + 64 + lane] = __float2half(acc);
}

// ---- kernel 3: attention + dst-tiled gather with ballot/ctz compaction ----
// Per tile: ONE lane-parallel range test + __ballot -> even-lane mask; extract
// the ~8 resident edges via ctz/clear-bit into statically-indexed register
// slots (up to 16 outstanding loads), then drain. No per-edge unrolled
// branches; tile phases preserve R6's L2 locality (FETCH ~272 MB).
__global__ __launch_bounds__(256) void k_edge(const float* __restrict__ ef,
                                              const int*   __restrict__ edges,
                                              const float* __restrict__ a_edge,
                                              const float* __restrict__ hn1,
                                              const float* __restrict__ hn2,
                                              const float* __restrict__ he1,
                                              const __half* __restrict__ hev,
                                              float* __restrict__ st,
                                              float* __restrict__ out) {
    const int t = threadIdx.x;
    const int w = t >> 6, l = t & 63;
    const int n = blockIdx.x * 4 + w;
    const int i = l >> 1, h = l & 1;          // lane pair (2i,2i+1) owns edge i
    const long ebase = (long)n * 32;

    // dst index first, then streaming ef loads (nt: single-use)
    const int d = __builtin_nontemporal_load(&edges[(ebase + i) * 2 + 1]);

    const f4v* efb = reinterpret_cast<const f4v*>(&ef[(ebase + i) * 32 + h * 16]);
    f4v v0 = __builtin_nontemporal_load(efb + 0);
    f4v v1 = __builtin_nontemporal_load(efb + 1);
    f4v v2 = __builtin_nontemporal_load(efb + 2);
    f4v v3 = __builtin_nontemporal_load(efb + 3);

    // attention compute
    float dot;
    {
        const float* ae = &a_edge[64 + h * 16];
        float4 a0q = *reinterpret_cast<const float4*>(ae);
        float4 a1q = *reinterpret_cast<const float4*>(ae + 4);
        float4 a2q = *reinterpret_cast<const float4*>(ae + 8);
        float4 a3q = *reinterpret_cast<const float4*>(ae + 12);
        dot = v0.x*a0q.x + v0.y*a0q.y + v0.z*a0q.z + v0.w*a0q.w
            + v1.x*a1q.x + v1.y*a1q.y + v1.z*a1q.z + v1.w*a1q.w
            + v2.x*a2q.x + v2.y*a2q.y + v2.z*a2q.z + v2.w*a2q.w
            + v3.x*a3q.x + v3.y*a3q.y + v3.z*a3q.z + v3.w*a3q.w;
    }
    dot += __shfl_xor(dot, 1);

    float attn = hn1[n] + hn2[d];
    attn = attn >= 0.f ? attn : ALPHA * attn;
    float wn = __expf(fminf(fmaxf(attn, -2.f), 2.f));

    float atte = he1[n] + dot;
    atte = atte >= 0.f ? atte : ALPHA * atte;
    float we = __expf(fminf(fmaxf(atte, -2.f), 2.f));

    float dn = wn, de = we;
    #pragma unroll
    for (int m = 2; m <= 32; m <<= 1) { dn += __shfl_xor(dn, m); de += __shfl_xor(de, m); }
    float nn = wn / dn, ne = we / de;

    float sqn = nn * nn, sqe = ne * ne;
    #pragma unroll
    for (int m = 2; m <= 32; m <<= 1) { sqn += __shfl_xor(sqn, m); sqe += __shfl_xor(sqe, m); }
    if (l == 0) { st[n] = sqn; st[NN + n] = sqe; }

    __half2 wpk = __floats2half2_rn(nn, ne);
    unsigned int wbits = *reinterpret_cast<unsigned int*>(&wpk);

    // tiled gather via ballot compaction
    const bool isE = l >= 32;
    float a0 = 0.f, a1 = 0.f;
    #pragma unroll
    for (int tile = 0; tile < TILES; ++tile) {
        const int lo = tile * TILE_N;
        const bool cond = (d >= lo) && (d < lo + TILE_N);
        unsigned long long bal = __ballot(cond) & 0x5555555555555555ULL;
        #pragma unroll
        for (int b = 0; b < 2; ++b) {          // 2 batches of 16 covers cnt<=32
            if (!bal) break;                   // wave-uniform early exit
            __half2 h2[16]; unsigned int wb[16]; bool vq[16];
            #pragma unroll
            for (int q = 0; q < 16; ++q) {
                vq[q] = (bal != 0);
                if (vq[q]) {
                    int s = (int)__builtin_ctzll(bal);
                    bal &= bal - 1;
                    int du = __builtin_amdgcn_readlane(d, s);
                    wb[q] = (unsigned int)__builtin_amdgcn_readlane((int)wbits, s);
                    h2[q] = *reinterpret_cast<const __half2*>(&hev[(long)du * 128 + l * 2]);
                }
            }
            #pragma unroll
            for (int q = 0; q < 16; ++q) {
                if (vq[q]) {
                    __half2 wp = *reinterpret_cast<__half2*>(&wb[q]);
                    float wt = isE ? __high2float(wp) : __low2float(wp);
                    float2 f = __half22float2(h2[q]);
                    a0 = fmaf(wt, f.x, a0);
                    a1 = fmaf(wt, f.y, a1);
                }
            }
        }
    }

    long off = isE ? ((long)NN * 64 + (long)n * 64 + (l - 32) * 2)
                   : ((long)n * 64 + l * 2);
    f2v o; o.x = a0; o.y = a1;
    __builtin_nontemporal_store(o, reinterpret_cast<f2v*>(&out[off]));
}

// ---- kernel 4a: stats reduction stage 1 ----
__global__ __launch_bounds__(256) void k_red1(const float* __restrict__ st,
                                              float* __restrict__ part) {
    const int t = threadIdx.x;
    const int n = blockIdx.x * 256 + t;
    float v0 = 0.f, v1 = 0.f;
    if (n < NN) { v0 = st[n]; v1 = st[NN + n]; }
    #pragma unroll
    for (int m = 1; m <= 32; m <<= 1) { v0 += __shfl_xor(v0, m); v1 += __shfl_xor(v1, m); }
    __shared__ float ls[4][2];
    const int wv = t >> 6;
    if ((t & 63) == 0) { ls[wv][0] = v0; ls[wv][1] = v1; }
    __syncthreads();
    if (t == 0) {
        part[(long)blockIdx.x * 2]     = ls[0][0] + ls[1][0] + ls[2][0] + ls[3][0];
        part[(long)blockIdx.x * 2 + 1] = ls[0][1] + ls[1][1] + ls[2][1] + ls[3][1];
    }
}

// ---- kernel 4b: final variances ----
__global__ __launch_bounds__(64) void k_red2(const float* __restrict__ part,
                                             float* __restrict__ out) {
    const int t = threadIdx.x;
    double v0 = 0.0, v1 = 0.0;
    for (int b = t; b < 196; b += 64) {
        v0 += (double)part[b * 2];
        v1 += (double)part[b * 2 + 1];
    }
    #pragma unroll
    for (int m = 1; m <= 32; m <<= 1) { v0 += __shfl_xor(v0, m); v1 += __shfl_xor(v1, m); }
    if (t == 0) {
        const double M = (double)NE;
        const double corr = (double)NN * (double)NN / M;   // (sum w)^2/M, sum w == NN
        out[6400000] = (float)((v0 - corr) / (M - 1.0));
        out[6400001] = (float)((v1 - corr) / (M - 1.0));
    }
}

extern "C" void kernel_launch(void* const* d_in, const int* in_sizes, int n_in,
                              void* d_out, int out_size, void* d_ws, size_t ws_size,
                              hipStream_t stream) {
    const float* node_fts = (const float*)d_in[0];
    const float* edge_fts = (const float*)d_in[1];
    const int*   edges    = (const int*)  d_in[2];
    const float* W_node   = (const float*)d_in[3];
    const float* W_edge   = (const float*)d_in[4];
    const float* a_node   = (const float*)d_in[5];
    const float* a_edge   = (const float*)d_in[6];
    float* out = (float*)d_out;
    float* ws  = (float*)d_ws;

    float*  hn1 = ws + WS_HN1;
    float*  hn2 = ws + WS_HN2;
    float*  he1 = ws + WS_HE1;
    float*  st  = ws + WS_ST;
    float*  prt = ws + WS_P;
    __half* hev = (__half*)(ws + WS_HEV);

    k_hv  <<<(NN + 63) / 64, 256, 0, stream>>>(node_fts, W_node, a_node, a_edge,
                                               hev, hn1, hn2, he1);
    k_ev  <<<NN / 4, 256, 0, stream>>>(edge_fts, W_edge, hev);
    k_edge<<<NN / 4, 256, 0, stream>>>(edge_fts, edges, a_edge, hn1, hn2, he1,
                                       hev, st, out);
    k_red1<<<196, 256, 0, stream>>>(st, prt);
    k_red2<<<1, 64, 0, stream>>>(prt, out);
}

// Round 8
// 164.225 us; speedup vs baseline: 1.2048x; 1.0116x over previous
//
#include <hip/hip_runtime.h>
#include <hip/hip_fp16.h>

#define ALPHA 0.2f
static constexpr int NN = 50000;
static constexpr long NE = (long)NN * 32;

typedef float f4v __attribute__((ext_vector_type(4)));
typedef float f2v __attribute__((ext_vector_type(2)));

// workspace layout (float offsets)
static constexpr long WS_HN1 = 0;
static constexpr long WS_HN2 = NN;
static constexpr long WS_HE1 = 2L * NN;
static constexpr long WS_ST  = 3L * NN;        // 2*NN: [sum nn^2][sum ne^2]
static constexpr long WS_P   = 5L * NN;        // 512 floats of partials
static constexpr long WS_HEV = 250560;         // __half[NN*128]; 250560*4 % 256 == 0

// ---- kernel 1: h_v GEMM (50000x256 @ 256x64) + f16 pack + attention dots ----
__global__ __launch_bounds__(256) void k_hv(const float* __restrict__ A,
                                            const float* __restrict__ W,
                                            const float* __restrict__ a_node,
                                            const float* __restrict__ a_edge,
                                            __half* __restrict__ hev,
                                            float* __restrict__ hn1,
                                            float* __restrict__ hn2,
                                            float* __restrict__ he1) {
    __shared__ float As[16][65];
    __shared__ float Ws[16][64];
    const int t  = threadIdx.x;
    const int m0 = blockIdx.x * 64;
    const int tr = t >> 4, tc = t & 15;
    const int lr = t >> 2, seg = t & 3;
    const int wk = t >> 4, wc = t & 15;

    float acc[4][4] = {};
    for (int k0 = 0; k0 < 256; k0 += 16) {
        int row = m0 + lr;
        float4 av = make_float4(0.f, 0.f, 0.f, 0.f);
        if (row < NN)
            av = *reinterpret_cast<const float4*>(&A[(long)row * 256 + k0 + seg * 4]);
        As[seg*4+0][lr] = av.x; As[seg*4+1][lr] = av.y;
        As[seg*4+2][lr] = av.z; As[seg*4+3][lr] = av.w;
        *reinterpret_cast<float4*>(&Ws[wk][wc*4]) =
            *reinterpret_cast<const float4*>(&W[(k0 + wk) * 64 + wc * 4]);
        __syncthreads();
        #pragma unroll
        for (int kk = 0; kk < 16; ++kk) {
            float a0 = As[kk][tr*4+0], a1 = As[kk][tr*4+1];
            float a2 = As[kk][tr*4+2], a3 = As[kk][tr*4+3];
            float b0 = Ws[kk][tc*4+0], b1 = Ws[kk][tc*4+1];
            float b2 = Ws[kk][tc*4+2], b3 = Ws[kk][tc*4+3];
            acc[0][0] += a0*b0; acc[0][1] += a0*b1; acc[0][2] += a0*b2; acc[0][3] += a0*b3;
            acc[1][0] += a1*b0; acc[1][1] += a1*b1; acc[1][2] += a1*b2; acc[1][3] += a1*b3;
            acc[2][0] += a2*b0; acc[2][1] += a2*b1; acc[2][2] += a2*b2; acc[2][3] += a2*b3;
            acc[3][0] += a3*b0; acc[3][1] += a3*b1; acc[3][2] += a3*b2; acc[3][3] += a3*b3;
        }
        __syncthreads();
    }

    float an1[4], an2[4], ae1[4];
    #pragma unroll
    for (int j = 0; j < 4; ++j) {
        an1[j] = a_node[tc*4 + j];
        an2[j] = a_node[64 + tc*4 + j];
        ae1[j] = a_edge[tc*4 + j];
    }

    #pragma unroll
    for (int q = 0; q < 4; ++q) {
        float p1 = 0.f, p2 = 0.f, p3 = 0.f;
        #pragma unroll
        for (int j = 0; j < 4; ++j) {
            p1 += acc[q][j] * an1[j];
            p2 += acc[q][j] * an2[j];
            p3 += acc[q][j] * ae1[j];
        }
        #pragma unroll
        for (int m = 1; m <= 8; m <<= 1) {
            p1 += __shfl_xor(p1, m);
            p2 += __shfl_xor(p2, m);
            p3 += __shfl_xor(p3, m);
        }
        int row = m0 + tr * 4 + q;
        if (row < NN) {
            ushort4 hp;
            hp.x = __half_as_ushort(__float2half(acc[q][0]));
            hp.y = __half_as_ushort(__float2half(acc[q][1]));
            hp.z = __half_as_ushort(__float2half(acc[q][2]));
            hp.w = __half_as_ushort(__float2half(acc[q][3]));
            *reinterpret_cast<ushort4*>(&hev[(long)row * 128 + tc * 4]) = hp;
            if (tc == 0) { hn1[row] = p1; hn2[row] = p2; he1[row] = p3; }
        }
    }
}

// ---- kernel 2: e_v rows 0..49999 -> f16 second half of hev ----
__global__ __launch_bounds__(256) void k_ev(const float* __restrict__ ef,
                                            const float* __restrict__ We,
                                            __half* __restrict__ hev) {
    const int lane = threadIdx.x & 63, w = threadIdx.x >> 6;
    const int r = blockIdx.x * 4 + w;
    float acc = 0.f;
    #pragma unroll
    for (int k = 0; k < 32; ++k)
        acc += ef[(long)r * 32 + k] * We[k * 64 + lane];
    hev[(long)r * 128 + 64 + lane] = __float2half(acc);
}

// ---- kernel 3: attention + dst-SORTED gather ----
// Per-wave bitonic sort of the 32 (dst, weight) pairs (~15 cmp-exchange
// stages), then the lean R5 drain in ascending-dst order. Sorted order ==
// tile phasing with infinitesimal tiles and ZERO per-tile bookkeeping: all
// concurrent waves sweep dst-space in the same order, keeping the active
// hev band L2/L3-resident (R6 proved phase coherence survives block churn).
__global__ __launch_bounds__(256) void k_edge(const float* __restrict__ ef,
                                              const int*   __restrict__ edges,
                                              const float* __restrict__ a_edge,
                                              const float* __restrict__ hn1,
                                              const float* __restrict__ hn2,
                                              const float* __restrict__ he1,
                                              const __half* __restrict__ hev,
                                              float* __restrict__ st,
                                              float* __restrict__ out) {
    const int t = threadIdx.x;
    const int w = t >> 6, l = t & 63;
    const int n = blockIdx.x * 4 + w;
    const int i = l >> 1, h = l & 1;          // lane pair (2i,2i+1) owns edge i
    const long ebase = (long)n * 32;

    // dst index first, then streaming ef loads (nt: single-use, protect L3)
    const int d = __builtin_nontemporal_load(&edges[(ebase + i) * 2 + 1]);

    const f4v* efb = reinterpret_cast<const f4v*>(&ef[(ebase + i) * 32 + h * 16]);
    f4v v0 = __builtin_nontemporal_load(efb + 0);
    f4v v1 = __builtin_nontemporal_load(efb + 1);
    f4v v2 = __builtin_nontemporal_load(efb + 2);
    f4v v3 = __builtin_nontemporal_load(efb + 3);

    // attention compute
    float dot;
    {
        const float* ae = &a_edge[64 + h * 16];
        float4 a0q = *reinterpret_cast<const float4*>(ae);
        float4 a1q = *reinterpret_cast<const float4*>(ae + 4);
        float4 a2q = *reinterpret_cast<const float4*>(ae + 8);
        float4 a3q = *reinterpret_cast<const float4*>(ae + 12);
        dot = v0.x*a0q.x + v0.y*a0q.y + v0.z*a0q.z + v0.w*a0q.w
            + v1.x*a1q.x + v1.y*a1q.y + v1.z*a1q.z + v1.w*a1q.w
            + v2.x*a2q.x + v2.y*a2q.y + v2.z*a2q.z + v2.w*a2q.w
            + v3.x*a3q.x + v3.y*a3q.y + v3.z*a3q.z + v3.w*a3q.w;
    }
    dot += __shfl_xor(dot, 1);

    float attn = hn1[n] + hn2[d];
    attn = attn >= 0.f ? attn : ALPHA * attn;
    float wn = __expf(fminf(fmaxf(attn, -2.f), 2.f));

    float atte = he1[n] + dot;
    atte = atte >= 0.f ? atte : ALPHA * atte;
    float we = __expf(fminf(fmaxf(atte, -2.f), 2.f));

    float dn = wn, de = we;
    #pragma unroll
    for (int m = 2; m <= 32; m <<= 1) { dn += __shfl_xor(dn, m); de += __shfl_xor(de, m); }
    float nn = wn / dn, ne = we / de;

    float sqn = nn * nn, sqe = ne * ne;
    #pragma unroll
    for (int m = 2; m <= 32; m <<= 1) { sqn += __shfl_xor(sqn, m); sqe += __shfl_xor(sqe, m); }
    if (l == 0) { st[n] = sqn; st[NN + n] = sqe; }

    __half2 wpk = __floats2half2_rn(nn, ne);
    unsigned int wbits = *reinterpret_cast<unsigned int*>(&wpk);

    // bitonic sort of 32 logical (d, w) pairs; pair lanes mirror every
    // compare-exchange so both lanes of a pair stay coherent.
    int sd = d;
    unsigned int sw = wbits;
    #pragma unroll
    for (int k = 2; k <= 32; k <<= 1) {
        #pragma unroll
        for (int j = k >> 1; j >= 1; j >>= 1) {
            int pd = __shfl_xor(sd, j << 1);
            unsigned int pw = (unsigned int)__shfl_xor((int)sw, j << 1);
            const bool iLower   = (i & j) == 0;
            const bool up       = (i & k) == 0;
            const bool want_min = (iLower == up);
            const bool take     = want_min ? (pd < sd) : (pd > sd);
            if (take) { sd = pd; sw = pw; }
        }
    }

    // lean drain in ascending-dst order (identical shape to R5's)
    const bool isE = l >= 32;
    __half2 h2[32];
    #pragma unroll
    for (int u = 0; u < 32; ++u) {
        int du = __builtin_amdgcn_readlane(sd, 2 * u);
        h2[u] = *reinterpret_cast<const __half2*>(&hev[(long)du * 128 + l * 2]);
    }
    float a0 = 0.f, a1 = 0.f;
    #pragma unroll
    for (int u = 0; u < 32; ++u) {
        unsigned int wv = (unsigned int)__builtin_amdgcn_readlane((int)sw, 2 * u);
        __half2 wp = *reinterpret_cast<__half2*>(&wv);
        float wt = isE ? __high2float(wp) : __low2float(wp);
        float2 f = __half22float2(h2[u]);
        a0 = fmaf(wt, f.x, a0);
        a1 = fmaf(wt, f.y, a1);
    }

    long off = isE ? ((long)NN * 64 + (long)n * 64 + (l - 32) * 2)
                   : ((long)n * 64 + l * 2);
    f2v o; o.x = a0; o.y = a1;
    __builtin_nontemporal_store(o, reinterpret_cast<f2v*>(&out[off]));
}

// ---- kernel 4a: stats reduction stage 1 ----
__global__ __launch_bounds__(256) void k_red1(const float* __restrict__ st,
                                              float* __restrict__ part) {
    const int t = threadIdx.x;
    const int n = blockIdx.x * 256 + t;
    float v0 = 0.f, v1 = 0.f;
    if (n < NN) { v0 = st[n]; v1 = st[NN + n]; }
    #pragma unroll
    for (int m = 1; m <= 32; m <<= 1) { v0 += __shfl_xor(v0, m); v1 += __shfl_xor(v1, m); }
    __shared__ float ls[4][2];
    const int wv = t >> 6;
    if ((t & 63) == 0) { ls[wv][0] = v0; ls[wv][1] = v1; }
    __syncthreads();
    if (t == 0) {
        part[(long)blockIdx.x * 2]     = ls[0][0] + ls[1][0] + ls[2][0] + ls[3][0];
        part[(long)blockIdx.x * 2 + 1] = ls[0][1] + ls[1][1] + ls[2][1] + ls[3][1];
    }
}

// ---- kernel 4b: final variances ----
__global__ __launch_bounds__(64) void k_red2(const float* __restrict__ part,
                                             float* __restrict__ out) {
    const int t = threadIdx.x;
    double v0 = 0.0, v1 = 0.0;
    for (int b = t; b < 196; b += 64) {
        v0 += (double)part[b * 2];
        v1 += (double)part[b * 2 + 1];
    }
    #pragma unroll
    for (int m = 1; m <= 32; m <<= 1) { v0 += __shfl_xor(v0, m); v1 += __shfl_xor(v1, m); }
    if (t == 0) {
        const double M = (double)NE;
        const double corr = (double)NN * (double)NN / M;   // (sum w)^2/M, sum w == NN
        out[6400000] = (float)((v0 - corr) / (M - 1.0));
        out[6400001] = (float)((v1 - corr) / (M - 1.0));
    }
}

extern "C" void kernel_launch(void* const* d_in, const int* in_sizes, int n_in,
                              void* d_out, int out_size, void* d_ws, size_t ws_size,
                              hipStream_t stream) {
    const float* node_fts = (const float*)d_in[0];
    const float* edge_fts = (const float*)d_in[1];
    const int*   edges    = (const int*)  d_in[2];
    const float* W_node   = (const float*)d_in[3];
    const float* W_edge   = (const float*)d_in[4];
    const float* a_node   = (const float*)d_in[5];
    const float* a_edge   = (const float*)d_in[6];
    float* out = (float*)d_out;
    float* ws  = (float*)d_ws;

    float*  hn1 = ws + WS_HN1;
    float*  hn2 = ws + WS_HN2;
    float*  he1 = ws + WS_HE1;
    float*  st  = ws + WS_ST;
    float*  prt = ws + WS_P;
    __half* hev = (__half*)(ws + WS_HEV);

    k_hv  <<<(NN + 63) / 64, 256, 0, stream>>>(node_fts, W_node, a_node, a_edge,
                                               hev, hn1, hn2, he1);
    k_ev  <<<NN / 4, 256, 0, stream>>>(edge_fts, W_edge, hev);
    k_edge<<<NN / 4, 256, 0, stream>>>(edge_fts, edges, a_edge, hn1, hn2, he1,
                                       hev, st, out);
    k_red1<<<196, 256, 0, stream>>>(st, prt);
    k_red2<<<1, 64, 0, stream>>>(prt, out);
}

// Round 9
// 162.833 us; speedup vs baseline: 1.2151x; 1.0085x over previous
//
#include <hip/hip_runtime.h>
#include <hip/hip_fp16.h>

#define ALPHA 0.2f
static constexpr int NN = 50000;
static constexpr long NE = (long)NN * 32;

typedef float f4v __attribute__((ext_vector_type(4)));
typedef float f2v __attribute__((ext_vector_type(2)));

// workspace layout (float offsets)
static constexpr long WS_HN1 = 0;
static constexpr long WS_HN2 = NN;
static constexpr long WS_HE1 = 2L * NN;
static constexpr long WS_ST  = 3L * NN;        // 2*NN: [sum nn^2][sum ne^2]
static constexpr long WS_P   = 5L * NN;        // 512 floats of partials
static constexpr long WS_HEV = 250560;         // __half[NN*128]; 250560*4 % 256 == 0

// ---- kernel 1: h_v GEMM (50000x256 @ 256x64) + f16 pack + attention dots ----
// LDS rows padded to 68 floats: 16B-aligned rows -> ds_read_b128 fragment
// loads (2 per kk instead of 8 scalar ds_read_b32).
__global__ __launch_bounds__(256) void k_hv(const float* __restrict__ A,
                                            const float* __restrict__ W,
                                            const float* __restrict__ a_node,
                                            const float* __restrict__ a_edge,
                                            __half* __restrict__ hev,
                                            float* __restrict__ hn1,
                                            float* __restrict__ hn2,
                                            float* __restrict__ he1) {
    __shared__ float As[16][68];
    __shared__ float Ws[16][68];
    const int t  = threadIdx.x;
    const int m0 = blockIdx.x * 64;
    const int tr = t >> 4, tc = t & 15;
    const int lr = t >> 2, seg = t & 3;
    const int wk = t >> 4, wc = t & 15;

    float acc[4][4] = {};
    for (int k0 = 0; k0 < 256; k0 += 16) {
        int row = m0 + lr;
        float4 av = make_float4(0.f, 0.f, 0.f, 0.f);
        if (row < NN)
            av = *reinterpret_cast<const float4*>(&A[(long)row * 256 + k0 + seg * 4]);
        As[seg*4+0][lr] = av.x; As[seg*4+1][lr] = av.y;
        As[seg*4+2][lr] = av.z; As[seg*4+3][lr] = av.w;
        *reinterpret_cast<float4*>(&Ws[wk][wc*4]) =
            *reinterpret_cast<const float4*>(&W[(k0 + wk) * 64 + wc * 4]);
        __syncthreads();
        #pragma unroll
        for (int kk = 0; kk < 16; ++kk) {
            float4 a4 = *reinterpret_cast<const float4*>(&As[kk][tr*4]);
            float4 b4 = *reinterpret_cast<const float4*>(&Ws[kk][tc*4]);
            acc[0][0] += a4.x*b4.x; acc[0][1] += a4.x*b4.y; acc[0][2] += a4.x*b4.z; acc[0][3] += a4.x*b4.w;
            acc[1][0] += a4.y*b4.x; acc[1][1] += a4.y*b4.y; acc[1][2] += a4.y*b4.z; acc[1][3] += a4.y*b4.w;
            acc[2][0] += a4.z*b4.x; acc[2][1] += a4.z*b4.y; acc[2][2] += a4.z*b4.z; acc[2][3] += a4.z*b4.w;
            acc[3][0] += a4.w*b4.x; acc[3][1] += a4.w*b4.y; acc[3][2] += a4.w*b4.z; acc[3][3] += a4.w*b4.w;
        }
        __syncthreads();
    }

    float an1[4], an2[4], ae1[4];
    #pragma unroll
    for (int j = 0; j < 4; ++j) {
        an1[j] = a_node[tc*4 + j];
        an2[j] = a_node[64 + tc*4 + j];
        ae1[j] = a_edge[tc*4 + j];
    }

    #pragma unroll
    for (int q = 0; q < 4; ++q) {
        float p1 = 0.f, p2 = 0.f, p3 = 0.f;
        #pragma unroll
        for (int j = 0; j < 4; ++j) {
            p1 += acc[q][j] * an1[j];
            p2 += acc[q][j] * an2[j];
            p3 += acc[q][j] * ae1[j];
        }
        #pragma unroll
        for (int m = 1; m <= 8; m <<= 1) {
            p1 += __shfl_xor(p1, m);
            p2 += __shfl_xor(p2, m);
            p3 += __shfl_xor(p3, m);
        }
        int row = m0 + tr * 4 + q;
        if (row < NN) {
            ushort4 hp;
            hp.x = __half_as_ushort(__float2half(acc[q][0]));
            hp.y = __half_as_ushort(__float2half(acc[q][1]));
            hp.z = __half_as_ushort(__float2half(acc[q][2]));
            hp.w = __half_as_ushort(__float2half(acc[q][3]));
            *reinterpret_cast<ushort4*>(&hev[(long)row * 128 + tc * 4]) = hp;
            if (tc == 0) { hn1[row] = p1; hn2[row] = p2; he1[row] = p3; }
        }
    }
}

// ---- kernel 2: e_v rows 0..49999 -> f16 second half of hev ----
__global__ __launch_bounds__(256) void k_ev(const float* __restrict__ ef,
                                            const float* __restrict__ We,
                                            __half* __restrict__ hev) {
    const int lane = threadIdx.x & 63, w = threadIdx.x >> 6;
    const int r = blockIdx.x * 4 + w;
    float acc = 0.f;
    #pragma unroll
    for (int k = 0; k < 32; ++k)
        acc += ef[(long)r * 32 + k] * We[k * 64 + lane];
    hev[(long)r * 128 + 64 + lane] = __float2half(acc);
}

// ---- kernel 3: attention + sorted CHUNKED gather ----
// Bitonic sort of the 32 (dst, weight) pairs, then drain in 4 chunks of 8
// ascending-dst edges. A fixed u-chunk of sorted edges == a dst-band of ~1/4
// of the table; consuming chunk c before issuing c+1 (sched_barrier pins the
// order) bounds each wave's active dst-window to ~2 bands (~6 MB) -> the hot
// band stays L2/L3-resident. R6's locality mechanism at R5's instruction
// count: no ballots, no range checks, readlane by constant.
__global__ __launch_bounds__(256) void k_edge(const float* __restrict__ ef,
                                              const int*   __restrict__ edges,
                                              const float* __restrict__ a_edge,
                                              const float* __restrict__ hn1,
                                              const float* __restrict__ hn2,
                                              const float* __restrict__ he1,
                                              const __half* __restrict__ hev,
                                              float* __restrict__ st,
                                              float* __restrict__ out) {
    const int t = threadIdx.x;
    const int w = t >> 6, l = t & 63;
    const int n = blockIdx.x * 4 + w;
    const int i = l >> 1, h = l & 1;          // lane pair (2i,2i+1) owns edge i
    const long ebase = (long)n * 32;

    // dst index first, then streaming ef loads (nt: single-use, protect L3)
    const int d = __builtin_nontemporal_load(&edges[(ebase + i) * 2 + 1]);

    const f4v* efb = reinterpret_cast<const f4v*>(&ef[(ebase + i) * 32 + h * 16]);
    f4v v0 = __builtin_nontemporal_load(efb + 0);
    f4v v1 = __builtin_nontemporal_load(efb + 1);
    f4v v2 = __builtin_nontemporal_load(efb + 2);
    f4v v3 = __builtin_nontemporal_load(efb + 3);

    // attention compute
    float dot;
    {
        const float* ae = &a_edge[64 + h * 16];
        float4 a0q = *reinterpret_cast<const float4*>(ae);
        float4 a1q = *reinterpret_cast<const float4*>(ae + 4);
        float4 a2q = *reinterpret_cast<const float4*>(ae + 8);
        float4 a3q = *reinterpret_cast<const float4*>(ae + 12);
        dot = v0.x*a0q.x + v0.y*a0q.y + v0.z*a0q.z + v0.w*a0q.w
            + v1.x*a1q.x + v1.y*a1q.y + v1.z*a1q.z + v1.w*a1q.w
            + v2.x*a2q.x + v2.y*a2q.y + v2.z*a2q.z + v2.w*a2q.w
            + v3.x*a3q.x + v3.y*a3q.y + v3.z*a3q.z + v3.w*a3q.w;
    }
    dot += __shfl_xor(dot, 1);

    float attn = hn1[n] + hn2[d];
    attn = attn >= 0.f ? attn : ALPHA * attn;
    float wn = __expf(fminf(fmaxf(attn, -2.f), 2.f));

    float atte = he1[n] + dot;
    atte = atte >= 0.f ? atte : ALPHA * atte;
    float we = __expf(fminf(fmaxf(atte, -2.f), 2.f));

    float dn = wn, de = we;
    #pragma unroll
    for (int m = 2; m <= 32; m <<= 1) { dn += __shfl_xor(dn, m); de += __shfl_xor(de, m); }
    float nn = wn / dn, ne = we / de;

    float sqn = nn * nn, sqe = ne * ne;
    #pragma unroll
    for (int m = 2; m <= 32; m <<= 1) { sqn += __shfl_xor(sqn, m); sqe += __shfl_xor(sqe, m); }
    if (l == 0) { st[n] = sqn; st[NN + n] = sqe; }

    __half2 wpk = __floats2half2_rn(nn, ne);
    unsigned int wbits = *reinterpret_cast<unsigned int*>(&wpk);

    // bitonic sort of 32 logical (d, w) pairs; pair lanes mirror every
    // compare-exchange so both lanes of a pair stay coherent.
    int sd = d;
    unsigned int sw = wbits;
    #pragma unroll
    for (int k = 2; k <= 32; k <<= 1) {
        #pragma unroll
        for (int j = k >> 1; j >= 1; j >>= 1) {
            int pd = __shfl_xor(sd, j << 1);
            unsigned int pw = (unsigned int)__shfl_xor((int)sw, j << 1);
            const bool iLower   = (i & j) == 0;
            const bool up       = (i & k) == 0;
            const bool want_min = (iLower == up);
            const bool take     = want_min ? (pd < sd) : (pd > sd);
            if (take) { sd = pd; sw = pw; }
        }
    }

    // chunked drain in ascending-dst order
    const bool isE = l >= 32;
    float a0 = 0.f, a1 = 0.f;
    #pragma unroll
    for (int c = 0; c < 4; ++c) {
        __half2 h2[8];
        #pragma unroll
        for (int u = 0; u < 8; ++u) {
            int du = __builtin_amdgcn_readlane(sd, 2 * (c * 8 + u));
            h2[u] = *reinterpret_cast<const __half2*>(&hev[(long)du * 128 + l * 2]);
        }
        #pragma unroll
        for (int u = 0; u < 8; ++u) {
            unsigned int wv = (unsigned int)__builtin_amdgcn_readlane((int)sw, 2 * (c * 8 + u));
            __half2 wp = *reinterpret_cast<__half2*>(&wv);
            float wt = isE ? __high2float(wp) : __low2float(wp);
            float2 f = __half22float2(h2[u]);
            a0 = fmaf(wt, f.x, a0);
            a1 = fmaf(wt, f.y, a1);
        }
        __builtin_amdgcn_sched_barrier(0);   // pin: no cross-chunk hoisting
    }

    long off = isE ? ((long)NN * 64 + (long)n * 64 + (l - 32) * 2)
                   : ((long)n * 64 + l * 2);
    f2v o; o.x = a0; o.y = a1;
    __builtin_nontemporal_store(o, reinterpret_cast<f2v*>(&out[off]));
}

// ---- kernel 4a: stats reduction stage 1 ----
__global__ __launch_bounds__(256) void k_red1(const float* __restrict__ st,
                                              float* __restrict__ part) {
    const int t = threadIdx.x;
    const int n = blockIdx.x * 256 + t;
    float v0 = 0.f, v1 = 0.f;
    if (n < NN) { v0 = st[n]; v1 = st[NN + n]; }
    #pragma unroll
    for (int m = 1; m <= 32; m <<= 1) { v0 += __shfl_xor(v0, m); v1 += __shfl_xor(v1, m); }
    __shared__ float ls[4][2];
    const int wv = t >> 6;
    if ((t & 63) == 0) { ls[wv][0] = v0; ls[wv][1] = v1; }
    __syncthreads();
    if (t == 0) {
        part[(long)blockIdx.x * 2]     = ls[0][0] + ls[1][0] + ls[2][0] + ls[3][0];
        part[(long)blockIdx.x * 2 + 1] = ls[0][1] + ls[1][1] + ls[2][1] + ls[3][1];
    }
}

// ---- kernel 4b: final variances ----
__global__ __launch_bounds__(64) void k_red2(const float* __restrict__ part,
                                             float* __restrict__ out) {
    const int t = threadIdx.x;
    double v0 = 0.0, v1 = 0.0;
    for (int b = t; b < 196; b += 64) {
        v0 += (double)part[b * 2];
        v1 += (double)part[b * 2 + 1];
    }
    #pragma unroll
    for (int m = 1; m <= 32; m <<= 1) { v0 += __shfl_xor(v0, m); v1 += __shfl_xor(v1, m); }
    if (t == 0) {
        const double M = (double)NE;
        const double corr = (double)NN * (double)NN / M;   // (sum w)^2/M, sum w == NN
        out[6400000] = (float)((v0 - corr) / (M - 1.0));
        out[6400001] = (float)((v1 - corr) / (M - 1.0));
    }
}

extern "C" void kernel_launch(void* const* d_in, const int* in_sizes, int n_in,
                              void* d_out, int out_size, void* d_ws, size_t ws_size,
                              hipStream_t stream) {
    const float* node_fts = (const float*)d_in[0];
    const float* edge_fts = (const float*)d_in[1];
    const int*   edges    = (const int*)  d_in[2];
    const float* W_node   = (const float*)d_in[3];
    const float* W_edge   = (const float*)d_in[4];
    const float* a_node   = (const float*)d_in[5];
    const float* a_edge   = (const float*)d_in[6];
    float* out = (float*)d_out;
    float* ws  = (float*)d_ws;

    float*  hn1 = ws + WS_HN1;
    float*  hn2 = ws + WS_HN2;
    float*  he1 = ws + WS_HE1;
    float*  st  = ws + WS_ST;
    float*  prt = ws + WS_P;
    __half* hev = (__half*)(ws + WS_HEV);

    k_hv  <<<(NN + 63) / 64, 256, 0, stream>>>(node_fts, W_node, a_node, a_edge,
                                               hev, hn1, hn2, he1);
    k_ev  <<<NN / 4, 256, 0, stream>>>(edge_fts, W_edge, hev);
    k_edge<<<NN / 4, 256, 0, stream>>>(edge_fts, edges, a_edge, hn1, hn2, he1,
                                       hev, st, out);
    k_red1<<<196, 256, 0, stream>>>(st, prt);
    k_red2<<<1, 64, 0, stream>>>(prt, out);
}

// Round 10
// 146.457 us; speedup vs baseline: 1.3509x; 1.1118x over previous
//
#include <hip/hip_runtime.h>
#include <hip/hip_fp16.h>

#define ALPHA 0.2f
static constexpr int NN = 50000;
static constexpr long NE = (long)NN * 32;

typedef float f4v __attribute__((ext_vector_type(4)));
typedef float f2v __attribute__((ext_vector_type(2)));
typedef _Float16 h8 __attribute__((ext_vector_type(8)));
typedef float f32x4 __attribute__((ext_vector_type(4)));

// workspace layout (float offsets)
static constexpr long WS_HN1 = 0;
static constexpr long WS_HN2 = NN;
static constexpr long WS_HE1 = 2L * NN;
static constexpr long WS_ST  = 3L * NN;        // 2*NN: [sum nn^2][sum ne^2]
static constexpr long WS_P   = 5L * NN;        // 512 floats of partials
static constexpr long WS_HEV = 250560;         // __half[NN*128]; 250560*4 % 256 == 0

// ---- kernel 1: h_v GEMM via MFMA f16 (operand swap: D = Wt · nf^T) ----
// Per block: 64 rows x 64 cols, K=256. Wave w owns rows [w*16, w*16+16),
// all 4 col-tiles. A-operand = Wt (LDS f16, lane: row n = l&15, k contiguous);
// B-operand = node_fts rows (global f32 -> f16 regs, lane: col m = l&15,
// k contiguous). Each node_fts row is read by exactly ONE block -> stream,
// no LDS staging for A. C/D: m = col = lane&15, n = row = (lane>>4)*4+reg.
__global__ __launch_bounds__(256) void k_hv(const float* __restrict__ A,
                                            const float* __restrict__ W,
                                            const float* __restrict__ a_node,
                                            const float* __restrict__ a_edge,
                                            __half* __restrict__ hev,
                                            float* __restrict__ hn1,
                                            float* __restrict__ hn2,
                                            float* __restrict__ he1) {
    __shared__ _Float16 Wt[64][264];           // [n][k], stride 264 (16B-aligned rows)
    const int t = threadIdx.x;
    const int w = t >> 6, l = t & 63;
    const int lm = l & 15, lq = l >> 4;

    // stage W^T into LDS as f16 (coalesced global reads; one-time)
    {
        const int n_ = t & 63, kq = t >> 6;
        #pragma unroll 8
        for (int j = 0; j < 64; ++j) {
            int k = kq * 64 + j;
            Wt[n_][k] = (_Float16)W[k * 64 + n_];
        }
    }
    __syncthreads();

    const int mbase = blockIdx.x * 64 + w * 16;
    const int m = mbase + lm;                  // this lane's output row (col j of D)
    const int arow = m < NN ? m : NN - 1;      // clamp: tail block reads row NN-1

    f32x4 acc[4] = {};
    #pragma unroll
    for (int s = 0; s < 8; ++s) {
        const int k0 = s * 32 + lq * 8;
        // B-operand: 8 contiguous k of node_fts[arow]
        float4 q0 = *reinterpret_cast<const float4*>(&A[(long)arow * 256 + k0]);
        float4 q1 = *reinterpret_cast<const float4*>(&A[(long)arow * 256 + k0 + 4]);
        h8 nf;
        nf[0] = (_Float16)q0.x; nf[1] = (_Float16)q0.y;
        nf[2] = (_Float16)q0.z; nf[3] = (_Float16)q0.w;
        nf[4] = (_Float16)q1.x; nf[5] = (_Float16)q1.y;
        nf[6] = (_Float16)q1.z; nf[7] = (_Float16)q1.w;
        // A-operand: Wt rows (n = c*16 + lm), 8 contiguous k -> ds_read_b128
        #pragma unroll
        for (int c = 0; c < 4; ++c) {
            h8 wf = *reinterpret_cast<const h8*>(&Wt[c * 16 + lm][k0]);
            acc[c] = __builtin_amdgcn_mfma_f32_16x16x32_f16(wf, nf, acc[c], 0, 0, 0);
        }
    }

    // epilogue: hev f16 store + attention dots from f32 acc
    float p1 = 0.f, p2 = 0.f, p3 = 0.f;
    #pragma unroll
    for (int c = 0; c < 4; ++c) {
        const int n0 = c * 16 + lq * 4;
        ushort4 hp;
        hp.x = __half_as_ushort(__float2half(acc[c][0]));
        hp.y = __half_as_ushort(__float2half(acc[c][1]));
        hp.z = __half_as_ushort(__float2half(acc[c][2]));
        hp.w = __half_as_ushort(__float2half(acc[c][3]));
        if (m < NN)
            *reinterpret_cast<ushort4*>(&hev[(long)m * 128 + n0]) = hp;
        #pragma unroll
        for (int r = 0; r < 4; ++r) {
            const int n = n0 + r;
            const float hv = acc[c][r];
            p1 += hv * a_node[n];
            p2 += hv * a_node[64 + n];
            p3 += hv * a_edge[n];
        }
    }
    // reduce across the 4 lanes sharing m (l, l+16, l+32, l+48)
    p1 += __shfl_xor(p1, 16); p1 += __shfl_xor(p1, 32);
    p2 += __shfl_xor(p2, 16); p2 += __shfl_xor(p2, 32);
    p3 += __shfl_xor(p3, 16); p3 += __shfl_xor(p3, 32);
    if (l < 16 && m < NN) { hn1[m] = p1; hn2[m] = p2; he1[m] = p3; }
}

// ---- kernel 2: e_v rows 0..49999 -> f16 second half of hev ----
__global__ __launch_bounds__(256) void k_ev(const float* __restrict__ ef,
                                            const float* __restrict__ We,
                                            __half* __restrict__ hev) {
    const int lane = threadIdx.x & 63, w = threadIdx.x >> 6;
    const int r = blockIdx.x * 4 + w;
    float acc = 0.f;
    #pragma unroll
    for (int k = 0; k < 32; ++k)
        acc += ef[(long)r * 32 + k] * We[k * 64 + lane];
    hev[(long)r * 128 + 64 + lane] = __float2half(acc);
}

// ---- kernel 3: attention + sorted chunked gather (R9 best-known form) ----
__global__ __launch_bounds__(256) void k_edge(const float* __restrict__ ef,
                                              const int*   __restrict__ edges,
                                              const float* __restrict__ a_edge,
                                              const float* __restrict__ hn1,
                                              const float* __restrict__ hn2,
                                              const float* __restrict__ he1,
                                              const __half* __restrict__ hev,
                                              float* __restrict__ st,
                                              float* __restrict__ out) {
    const int t = threadIdx.x;
    const int w = t >> 6, l = t & 63;
    const int n = blockIdx.x * 4 + w;
    const int i = l >> 1, h = l & 1;          // lane pair (2i,2i+1) owns edge i
    const long ebase = (long)n * 32;

    const int d = __builtin_nontemporal_load(&edges[(ebase + i) * 2 + 1]);

    const f4v* efb = reinterpret_cast<const f4v*>(&ef[(ebase + i) * 32 + h * 16]);
    f4v v0 = __builtin_nontemporal_load(efb + 0);
    f4v v1 = __builtin_nontemporal_load(efb + 1);
    f4v v2 = __builtin_nontemporal_load(efb + 2);
    f4v v3 = __builtin_nontemporal_load(efb + 3);

    float dot;
    {
        const float* ae = &a_edge[64 + h * 16];
        float4 a0q = *reinterpret_cast<const float4*>(ae);
        float4 a1q = *reinterpret_cast<const float4*>(ae + 4);
        float4 a2q = *reinterpret_cast<const float4*>(ae + 8);
        float4 a3q = *reinterpret_cast<const float4*>(ae + 12);
        dot = v0.x*a0q.x + v0.y*a0q.y + v0.z*a0q.z + v0.w*a0q.w
            + v1.x*a1q.x + v1.y*a1q.y + v1.z*a1q.z + v1.w*a1q.w
            + v2.x*a2q.x + v2.y*a2q.y + v2.z*a2q.z + v2.w*a2q.w
            + v3.x*a3q.x + v3.y*a3q.y + v3.z*a3q.z + v3.w*a3q.w;
    }
    dot += __shfl_xor(dot, 1);

    float attn = hn1[n] + hn2[d];
    attn = attn >= 0.f ? attn : ALPHA * attn;
    float wn = __expf(fminf(fmaxf(attn, -2.f), 2.f));

    float atte = he1[n] + dot;
    atte = atte >= 0.f ? atte : ALPHA * atte;
    float we = __expf(fminf(fmaxf(atte, -2.f), 2.f));

    float dn = wn, de = we;
    #pragma unroll
    for (int m = 2; m <= 32; m <<= 1) { dn += __shfl_xor(dn, m); de += __shfl_xor(de, m); }
    float nn = wn / dn, ne = we / de;

    float sqn = nn * nn, sqe = ne * ne;
    #pragma unroll
    for (int m = 2; m <= 32; m <<= 1) { sqn += __shfl_xor(sqn, m); sqe += __shfl_xor(sqe, m); }
    if (l == 0) { st[n] = sqn; st[NN + n] = sqe; }

    __half2 wpk = __floats2half2_rn(nn, ne);
    unsigned int wbits = *reinterpret_cast<unsigned int*>(&wpk);

    // bitonic sort of 32 logical (d, w) pairs (pair lanes mirror exchanges)
    int sd = d;
    unsigned int sw = wbits;
    #pragma unroll
    for (int k = 2; k <= 32; k <<= 1) {
        #pragma unroll
        for (int j = k >> 1; j >= 1; j >>= 1) {
            int pd = __shfl_xor(sd, j << 1);
            unsigned int pw = (unsigned int)__shfl_xor((int)sw, j << 1);
            const bool iLower   = (i & j) == 0;
            const bool up       = (i & k) == 0;
            const bool want_min = (iLower == up);
            const bool take     = want_min ? (pd < sd) : (pd > sd);
            if (take) { sd = pd; sw = pw; }
        }
    }

    // chunked drain in ascending-dst order
    const bool isE = l >= 32;
    float a0 = 0.f, a1 = 0.f;
    #pragma unroll
    for (int c = 0; c < 4; ++c) {
        __half2 h2[8];
        #pragma unroll
        for (int u = 0; u < 8; ++u) {
            int du = __builtin_amdgcn_readlane(sd, 2 * (c * 8 + u));
            h2[u] = *reinterpret_cast<const __half2*>(&hev[(long)du * 128 + l * 2]);
        }
        #pragma unroll
        for (int u = 0; u < 8; ++u) {
            unsigned int wv = (unsigned int)__builtin_amdgcn_readlane((int)sw, 2 * (c * 8 + u));
            __half2 wp = *reinterpret_cast<__half2*>(&wv);
            float wt = isE ? __high2float(wp) : __low2float(wp);
            float2 f = __half22float2(h2[u]);
            a0 = fmaf(wt, f.x, a0);
            a1 = fmaf(wt, f.y, a1);
        }
        __builtin_amdgcn_sched_barrier(0);   // pin: no cross-chunk hoisting
    }

    long off = isE ? ((long)NN * 64 + (long)n * 64 + (l - 32) * 2)
                   : ((long)n * 64 + l * 2);
    f2v o; o.x = a0; o.y = a1;
    __builtin_nontemporal_store(o, reinterpret_cast<f2v*>(&out[off]));
}

// ---- kernel 4a: stats reduction stage 1 ----
__global__ __launch_bounds__(256) void k_red1(const float* __restrict__ st,
                                              float* __restrict__ part) {
    const int t = threadIdx.x;
    const int n = blockIdx.x * 256 + t;
    float v0 = 0.f, v1 = 0.f;
    if (n < NN) { v0 = st[n]; v1 = st[NN + n]; }
    #pragma unroll
    for (int m = 1; m <= 32; m <<= 1) { v0 += __shfl_xor(v0, m); v1 += __shfl_xor(v1, m); }
    __shared__ float ls[4][2];
    const int wv = t >> 6;
    if ((t & 63) == 0) { ls[wv][0] = v0; ls[wv][1] = v1; }
    __syncthreads();
    if (t == 0) {
        part[(long)blockIdx.x * 2]     = ls[0][0] + ls[1][0] + ls[2][0] + ls[3][0];
        part[(long)blockIdx.x * 2 + 1] = ls[0][1] + ls[1][1] + ls[2][1] + ls[3][1];
    }
}

// ---- kernel 4b: final variances ----
__global__ __launch_bounds__(64) void k_red2(const float* __restrict__ part,
                                             float* __restrict__ out) {
    const int t = threadIdx.x;
    double v0 = 0.0, v1 = 0.0;
    for (int b = t; b < 196; b += 64) {
        v0 += (double)part[b * 2];
        v1 += (double)part[b * 2 + 1];
    }
    #pragma unroll
    for (int m = 1; m <= 32; m <<= 1) { v0 += __shfl_xor(v0, m); v1 += __shfl_xor(v1, m); }
    if (t == 0) {
        const double M = (double)NE;
        const double corr = (double)NN * (double)NN / M;   // (sum w)^2/M, sum w == NN
        out[6400000] = (float)((v0 - corr) / (M - 1.0));
        out[6400001] = (float)((v1 - corr) / (M - 1.0));
    }
}

extern "C" void kernel_launch(void* const* d_in, const int* in_sizes, int n_in,
                              void* d_out, int out_size, void* d_ws, size_t ws_size,
                              hipStream_t stream) {
    const float* node_fts = (const float*)d_in[0];
    const float* edge_fts = (const float*)d_in[1];
    const int*   edges    = (const int*)  d_in[2];
    const float* W_node   = (const float*)d_in[3];
    const float* W_edge   = (const float*)d_in[4];
    const float* a_node   = (const float*)d_in[5];
    const float* a_edge   = (const float*)d_in[6];
    float* out = (float*)d_out;
    float* ws  = (float*)d_ws;

    float*  hn1 = ws + WS_HN1;
    float*  hn2 = ws + WS_HN2;
    float*  he1 = ws + WS_HE1;
    float*  st  = ws + WS_ST;
    float*  prt = ws + WS_P;
    __half* hev = (__half*)(ws + WS_HEV);

    k_hv  <<<(NN + 63) / 64, 256, 0, stream>>>(node_fts, W_node, a_node, a_edge,
                                               hev, hn1, hn2, he1);
    k_ev  <<<NN / 4, 256, 0, stream>>>(edge_fts, W_edge, hev);
    k_edge<<<NN / 4, 256, 0, stream>>>(edge_fts, edges, a_edge, hn1, hn2, he1,
                                       hev, st, out);
    k_red1<<<196, 256, 0, stream>>>(st, prt);
    k_red2<<<1, 64, 0, stream>>>(prt, out);
}